// Round 1
// baseline (17.998 us; speedup 1.0000x reference)
//
#include <hip/hip_runtime.h>
#include <hip/hip_bf16.h>

#define DIM 1024

// Block layout for k_prep:
//   blocks [0, erow_blocks): e_score rows, 4 rows/block (1 wave each)
//   blocks [erow_blocks, erow_blocks+64): q_term partials, 32 Wq-rows each
__global__ void k_prep(const int* __restrict__ subject,
                       const int* __restrict__ relation,
                       const float* __restrict__ ent,
                       const float* __restrict__ rel,
                       const float* __restrict__ Wq,
                       const float* __restrict__ bq,
                       const float* __restrict__ Ws,
                       float* __restrict__ qpart,
                       float* __restrict__ escore,
                       int n_ent, int erow_blocks) {
    const int bid = blockIdx.x;
    const int tid = threadIdx.x;

    if (bid < erow_blocks) {
        // ---- e_score[row] = ent[row] . Ws[D:] ----
        const int wid  = tid >> 6;
        const int lane = tid & 63;
        const int row  = bid * 4 + wid;
        if (row < n_ent) {
            const float* rp = ent + (size_t)row * DIM;
            const float* wc = Ws + DIM;
            float acc = 0.f;
#pragma unroll
            for (int it = 0; it < 4; ++it) {
                const int j = (it * 64 + lane) * 4;
                float4 a = *(const float4*)(rp + j);
                float4 w = *(const float4*)(wc + j);
                acc += a.x * w.x + a.y * w.y + a.z * w.z + a.w * w.w;
            }
#pragma unroll
            for (int off = 32; off; off >>= 1) acc += __shfl_down(acc, off, 64);
            if (lane == 0) escore[row] = acc;
        }
    } else {
        // ---- q_term partial over Wq rows [b*32, b*32+32) ----
        const int b = bid - erow_blocks;           // 0..63
        const int s = subject[0];
        const int r = relation[0];
        const int j = tid * 4;                     // this thread's 4 columns
        float4 acc = make_float4(0.f, 0.f, 0.f, 0.f);
        const int k0 = b * 32;
#pragma unroll 4
        for (int kk = 0; kk < 32; ++kk) {
            const int k = k0 + kk;
            const float c = (k < DIM) ? ent[(size_t)s * DIM + k]
                                      : rel[(size_t)r * DIM + (k - DIM)];
            float4 wrow = *(const float4*)(Wq + (size_t)k * DIM + j);
            acc.x += c * wrow.x; acc.y += c * wrow.y;
            acc.z += c * wrow.z; acc.w += c * wrow.w;
        }
        float4 wt = *(const float4*)(Ws + j);      // Ws[:D] slice
        float p = acc.x * wt.x + acc.y * wt.y + acc.z * wt.z + acc.w * wt.w;
        if (b == 0) {                              // bq . Ws[:D] added once
            float4 bqv = *(const float4*)(bq + j);
            p += bqv.x * wt.x + bqv.y * wt.y + bqv.z * wt.z + bqv.w * wt.w;
        }
#pragma unroll
        for (int off = 32; off; off >>= 1) p += __shfl_down(p, off, 64);
        __shared__ float sp[4];
        const int wid  = tid >> 6;
        const int lane = tid & 63;
        if (lane == 0) sp[wid] = p;
        __syncthreads();
        if (tid == 0) qpart[b] = sp[0] + sp[1] + sp[2] + sp[3];
    }
}

__global__ void k_score(const int* __restrict__ cand,
                        const float* __restrict__ escore,
                        const float* __restrict__ qpart,
                        const float* __restrict__ bs,
                        float* __restrict__ out, int n) {
    __shared__ float s_qt;
    const int tid = threadIdx.x;
    if (tid < 64) {                                // wave 0 reduces the 64 partials
        float v = qpart[tid];
#pragma unroll
        for (int off = 32; off; off >>= 1) v += __shfl_down(v, off, 64);
        if (tid == 0) s_qt = v + bs[0];
    }
    __syncthreads();
    const int i = blockIdx.x * blockDim.x + tid;
    if (i < n) {
        const float x = s_qt + escore[cand[i]];
        out[i] = 1.f / (1.f + expf(-x));
    }
}

extern "C" void kernel_launch(void* const* d_in, const int* in_sizes, int n_in,
                              void* d_out, int out_size, void* d_ws, size_t ws_size,
                              hipStream_t stream) {
    const int*   subject  = (const int*)d_in[0];
    const int*   relation = (const int*)d_in[1];
    const int*   cand     = (const int*)d_in[2];
    const float* ent      = (const float*)d_in[3];
    const float* rel      = (const float*)d_in[4];
    const float* Wq       = (const float*)d_in[5];
    const float* bq       = (const float*)d_in[6];
    const float* Ws       = (const float*)d_in[7];
    const float* bs       = (const float*)d_in[8];

    const int n_ent  = in_sizes[3] / DIM;          // 10000
    const int n_cand = in_sizes[2];                // 131072

    float* qpart  = (float*)d_ws;                  // 64 floats
    float* escore = qpart + 64;                    // n_ent floats

    const int erow_blocks = (n_ent + 3) / 4;       // 2500
    k_prep<<<erow_blocks + 64, 256, 0, stream>>>(subject, relation, ent, rel,
                                                 Wq, bq, Ws, qpart, escore,
                                                 n_ent, erow_blocks);
    k_score<<<(n_cand + 255) / 256, 256, 0, stream>>>(cand, escore, qpart, bs,
                                                      (float*)d_out, n_cand);
}